// Round 5
// baseline (43501.355 us; speedup 1.0000x reference)
//
#include <hip/hip_runtime.h>
#include <math.h>

#define Bb 128
#define Nn 100
#define Ee 512
#define Hh 8
#define DHd 64
#define FFf 2048
#define Ll 6
#define STEPS 150
#define NBLK 128

typedef _Float16 h8 __attribute__((ext_vector_type(8)));
typedef _Float16 h4 __attribute__((ext_vector_type(4)));
typedef float f4 __attribute__((ext_vector_type(4)));

// ---------------------------------------------------------------------------
// Split-f16 MFMA GEMM (encoder + prep).  C = A@B via Ah*Bh + Ah*Bl + Al*Bh.
// ---------------------------------------------------------------------------
template<bool RELU, bool BIAS, bool OUTF32, bool SPLITK>
__global__ __launch_bounds__(256) void mgemm_k(
    const _Float16* __restrict__ Ah, const _Float16* __restrict__ Al, int lda,
    const _Float16* __restrict__ Bh, const _Float16* __restrict__ Bl, int ldb,
    float* __restrict__ C, _Float16* __restrict__ Ch, _Float16* __restrict__ Cl,
    int ldc, const float* __restrict__ bias, int K, int kc, int Mtot)
{
  __shared__ _Float16 sm[4 * 5120];
  _Float16* sAh = sm;
  _Float16* sAl = sm + 5120;
  _Float16* sBh = sm + 10240;
  _Float16* sBl = sm + 15360;
  const int tid = threadIdx.x;
  const int m0 = blockIdx.y * 128, n0 = blockIdx.x * 128;
  const int k0 = SPLITK ? blockIdx.z * kc : 0;
  const int kEnd = SPLITK ? (k0 + kc) : K;
  const int lane = tid & 63, wave = tid >> 6;
  const int wm = wave >> 1, wn = wave & 1;
  const int m16 = lane & 15, kg = lane >> 4;
  f4 acc[4][4];
#pragma unroll
  for (int i = 0; i < 4; ++i)
#pragma unroll
    for (int j = 0; j < 4; ++j) acc[i][j] = (f4)0.f;

  for (int kt = k0; kt < kEnd; kt += 32) {
#pragma unroll
    for (int it = 0; it < 2; ++it) {
      int idx = tid + it * 256;
      int row = idx >> 2, g = idx & 3;
      int lo_ = row * 40 + g * 8;
      size_t ga = (size_t)(m0 + row) * lda + kt + g * 8;
      size_t gb = (size_t)(n0 + row) * ldb + kt + g * 8;
      *(h8*)(sAh + lo_) = *(const h8*)(Ah + ga);
      *(h8*)(sAl + lo_) = *(const h8*)(Al + ga);
      *(h8*)(sBh + lo_) = *(const h8*)(Bh + gb);
      *(h8*)(sBl + lo_) = *(const h8*)(Bl + gb);
    }
    __syncthreads();
    h8 a_h[4], a_l[4], b_h[4], b_l[4];
#pragma unroll
    for (int i = 0; i < 4; ++i) {
      int ro = (wm * 64 + i * 16 + m16) * 40 + kg * 8;
      int co = (wn * 64 + i * 16 + m16) * 40 + kg * 8;
      a_h[i] = *(const h8*)(sAh + ro);
      a_l[i] = *(const h8*)(sAl + ro);
      b_h[i] = *(const h8*)(sBh + co);
      b_l[i] = *(const h8*)(sBl + co);
    }
#pragma unroll
    for (int i = 0; i < 4; ++i)
#pragma unroll
      for (int j = 0; j < 4; ++j) {
        acc[i][j] = __builtin_amdgcn_mfma_f32_16x16x32_f16(a_h[i], b_h[j], acc[i][j], 0, 0, 0);
        acc[i][j] = __builtin_amdgcn_mfma_f32_16x16x32_f16(a_h[i], b_l[j], acc[i][j], 0, 0, 0);
        acc[i][j] = __builtin_amdgcn_mfma_f32_16x16x32_f16(a_l[i], b_h[j], acc[i][j], 0, 0, 0);
      }
    __syncthreads();
  }

  float* Cz = OUTF32 ? (C + (SPLITK ? (size_t)blockIdx.z * (size_t)Mtot * ldc : (size_t)0)) : C;
  int rb = m0 + wm * 64 + kg * 4;
  int cb = n0 + wn * 64 + m16;
#pragma unroll
  for (int j = 0; j < 4; ++j) {
    int col = cb + j * 16;
    float bv = BIAS ? bias[col] : 0.f;
#pragma unroll
    for (int i = 0; i < 4; ++i) {
#pragma unroll
      for (int r = 0; r < 4; ++r) {
        float v = acc[i][j][r] + bv;
        if (RELU) v = fmaxf(v, 0.f);
        int row = rb + i * 16 + r;
        if (OUTF32) {
          Cz[(size_t)row * ldc + col] = v;
        } else {
          _Float16 hh = (_Float16)v;
          Ch[(size_t)row * ldc + col] = hh;
          Cl[(size_t)row * ldc + col] = (_Float16)(v - (float)hh);
        }
      }
    }
  }
}

// ---------------------------------------------------------------------------
// Weight transpose + split:  W [K][N] fp32 -> Th/Tl [N][K] f16
// ---------------------------------------------------------------------------
__global__ __launch_bounds__(256) void wconv_k(
    const float* __restrict__ W, int K, int N,
    _Float16* __restrict__ Th, _Float16* __restrict__ Tl)
{
  __shared__ float t[32][33];
  int n0 = blockIdx.x * 32, k0 = blockIdx.y * 32;
  int tid = threadIdx.x;
  int r = tid >> 3, c4 = (tid & 7) * 4;
  float4 v = *(const float4*)(W + (size_t)(k0 + r) * N + n0 + c4);
  t[r][c4 + 0] = v.x; t[r][c4 + 1] = v.y; t[r][c4 + 2] = v.z; t[r][c4 + 3] = v.w;
  __syncthreads();
  h4 hi, lo;
#pragma unroll
  for (int i = 0; i < 4; ++i) {
    float x = t[c4 + i][r];
    _Float16 hh = (_Float16)x;
    hi[i] = hh;
    lo[i] = (_Float16)(x - (float)hh);
  }
  *(h4*)(Th + (size_t)(n0 + r) * K + k0 + c4) = hi;
  *(h4*)(Tl + (size_t)(n0 + r) * K + k0 + c4) = lo;
}

// Stacked transpose+split: [wih(512xN); whh(512xN)] -> Th/Tl [N][1024]
__global__ __launch_bounds__(256) void wconv2_k(
    const float* __restrict__ Wa, const float* __restrict__ Wb,
    int N, _Float16* __restrict__ Th, _Float16* __restrict__ Tl)
{
  __shared__ float t[32][33];
  int n0 = blockIdx.x * 32, k0 = blockIdx.y * 32;
  int tid = threadIdx.x;
  int r = tid >> 3, c4 = (tid & 7) * 4;
  int kg = k0 + r;
  const float* src = (kg < 512) ? (Wa + (size_t)kg * N) : (Wb + (size_t)(kg - 512) * N);
  float4 v = *(const float4*)(src + n0 + c4);
  t[r][c4 + 0] = v.x; t[r][c4 + 1] = v.y; t[r][c4 + 2] = v.z; t[r][c4 + 3] = v.w;
  __syncthreads();
  h4 hi, lo;
#pragma unroll
  for (int i = 0; i < 4; ++i) {
    float x = t[c4 + i][r];
    _Float16 hh = (_Float16)x;
    hi[i] = hh;
    lo[i] = (_Float16)(x - (float)hh);
  }
  *(h4*)(Th + (size_t)(n0 + r) * 1024 + k0 + c4) = hi;
  *(h4*)(Tl + (size_t)(n0 + r) * 1024 + k0 + c4) = lo;
}

// plain elementwise split (no transpose)
__global__ __launch_bounds__(256) void wsplit_k(
    const float* __restrict__ W, _Float16* __restrict__ Th, _Float16* __restrict__ Tl, int n)
{
  int i = blockIdx.x * 256 + threadIdx.x;
  if (i < n) {
    float x = W[i];
    _Float16 hh = (_Float16)x;
    Th[i] = hh;
    Tl[i] = (_Float16)(x - (float)hh);
  }
}

// FF2 split-K(4) partial reduce + bias
__global__ __launch_bounds__(256) void reduce4_k(
    const float* __restrict__ P, const float* __restrict__ bias, float* __restrict__ out)
{
  int idx = blockIdx.x * 256 + threadIdx.x;
  const size_t S = 3200ull * 512;
  float v = P[idx] + P[idx + S] + P[idx + 2 * S] + P[idx + 3 * S] + bias[idx & 511];
  out[idx] = v;
}

// ---------------------------------------------------------------------------
__global__ __launch_bounds__(256) void input_proj_k(
    const float* __restrict__ nf, const float* __restrict__ inw,
    const float* __restrict__ inb, const float* __restrict__ pe,
    float* __restrict__ x, _Float16* __restrict__ xh, _Float16* __restrict__ xl)
{
  int idx = blockIdx.x * 256 + threadIdx.x;
  int bn = idx >> 9, e = idx & 511;
  int n = bn - (bn / Nn) * Nn;
  const float* fr = nf + (size_t)bn * 8;
  float s = inb[e] + pe[(size_t)n * 512 + e];
#pragma unroll
  for (int i = 0; i < 8; ++i) s += fr[i] * inw[(size_t)i * 512 + e];
  x[idx] = s;
  _Float16 hh = (_Float16)s;
  xh[idx] = hh;
  xl[idx] = (_Float16)(s - (float)hh);
}

__global__ __launch_bounds__(256) void ln_k(
    const float* __restrict__ xin, const float* __restrict__ yin,
    const float* __restrict__ g, const float* __restrict__ bb,
    float* __restrict__ out, _Float16* __restrict__ oh, _Float16* __restrict__ ol)
{
  int row = blockIdx.x, t = threadIdx.x;
  __shared__ float red[256];
  size_t base = (size_t)row * 512;
  float v0 = xin[base + t] + yin[base + t];
  float v1 = xin[base + 256 + t] + yin[base + 256 + t];
  red[t] = v0 + v1;
  __syncthreads();
  for (int o = 128; o > 0; o >>= 1) { if (t < o) red[t] += red[t + o]; __syncthreads(); }
  float mu = red[0] * (1.f / 512.f);
  __syncthreads();
  float d0 = v0 - mu, d1 = v1 - mu;
  red[t] = d0 * d0 + d1 * d1;
  __syncthreads();
  for (int o = 128; o > 0; o >>= 1) { if (t < o) red[t] += red[t + o]; __syncthreads(); }
  float inv = 1.f / sqrtf(red[0] * (1.f / 512.f) + 1e-5f);
  float y0 = d0 * inv * g[t] + bb[t];
  float y1 = d1 * inv * g[t + 256] + bb[t + 256];
  out[base + t] = y0;
  out[base + 256 + t] = y1;
  _Float16 h0 = (_Float16)y0, h1 = (_Float16)y1;
  oh[base + t] = h0;           ol[base + t] = (_Float16)(y0 - (float)h0);
  oh[base + 256 + t] = h1;     ol[base + 256 + t] = (_Float16)(y1 - (float)h1);
}

// ---------------------------------------------------------------------------
__global__ __launch_bounds__(256) void enc_attn_k(
    const float* __restrict__ q, const float* __restrict__ k,
    const float* __restrict__ v, _Float16* __restrict__ oh, _Float16* __restrict__ ol)
{
  __shared__ __align__(16) float smem[14848];
  int bh = blockIdx.x; int b = bh >> 3, h = bh & 7;
  int t = threadIdx.x;
  float* qs = smem;
  float* kT = smem + 7616;
  float* p  = smem;
  const float* qg = q + ((size_t)b * Nn) * 512 + h * 64;
  const float* kg = k + ((size_t)b * Nn) * 512 + h * 64;
  const float* vg = v + ((size_t)b * Nn) * 512 + h * 64;
  for (int idx = t; idx < 6400; idx += 256) {
    int i = idx >> 6, d = idx & 63;
    qs[i * 68 + d]  = qg[(size_t)i * 512 + d];
    kT[d * 113 + i] = kg[(size_t)i * 512 + d];
  }
  __syncthreads();
  int ti = t >> 4, tj = t & 15;
  int i0 = ti * 7, j0 = tj * 7;
  float s[7][7];
#pragma unroll
  for (int r = 0; r < 7; ++r)
#pragma unroll
    for (int c = 0; c < 7; ++c) s[r][c] = 0.f;
  for (int kk = 0; kk < 64; ++kk) {
    float a[7], bb[7];
#pragma unroll
    for (int r = 0; r < 7; ++r) a[r] = qs[(i0 + r) * 68 + kk];
#pragma unroll
    for (int c = 0; c < 7; ++c) bb[c] = kT[kk * 113 + j0 + c];
#pragma unroll
    for (int r = 0; r < 7; ++r)
#pragma unroll
      for (int c = 0; c < 7; ++c) s[r][c] += a[r] * bb[c];
  }
  __syncthreads();
#pragma unroll
  for (int r = 0; r < 7; ++r)
#pragma unroll
    for (int c = 0; c < 7; ++c) {
      int i = i0 + r, j = j0 + c;
      if (i < Nn && j < Nn) p[i * 104 + j] = s[r][c] * 0.125f;
    }
  __syncthreads();
  int w = t >> 6, lane = t & 63;
  for (int i = w; i < Nn; i += 4) {
    float x0 = p[i * 104 + lane];
    float x1 = (lane < 36) ? p[i * 104 + 64 + lane] : -3.4e38f;
    float mx = fmaxf(x0, x1);
    for (int msk = 32; msk; msk >>= 1) mx = fmaxf(mx, __shfl_xor(mx, msk));
    float e0 = expf(x0 - mx);
    float e1 = (lane < 36) ? expf(x1 - mx) : 0.f;
    float ss = e0 + e1;
    for (int msk = 32; msk; msk >>= 1) ss += __shfl_xor(ss, msk);
    p[i * 104 + lane] = e0 / ss;
    if (lane < 36) p[i * 104 + 64 + lane] = e1 / ss;
  }
  __syncthreads();
  int d0 = tj * 4;
  float oa[7][4];
#pragma unroll
  for (int r = 0; r < 7; ++r)
#pragma unroll
    for (int c = 0; c < 4; ++c) oa[r][c] = 0.f;
  for (int j = 0; j < Nn; ++j) {
    float pr[7];
#pragma unroll
    for (int r = 0; r < 7; ++r) pr[r] = p[(i0 + r) * 104 + j];
    float4 vv = *(const float4*)(vg + (size_t)j * 512 + d0);
#pragma unroll
    for (int r = 0; r < 7; ++r) {
      oa[r][0] += pr[r] * vv.x; oa[r][1] += pr[r] * vv.y;
      oa[r][2] += pr[r] * vv.z; oa[r][3] += pr[r] * vv.w;
    }
  }
  size_t ob = ((size_t)b * Nn) * 512 + h * 64 + d0;
#pragma unroll
  for (int r = 0; r < 7; ++r)
    if (i0 + r < Nn) {
      h4 hv, lv;
#pragma unroll
      for (int c = 0; c < 4; ++c) {
        _Float16 hh = (_Float16)oa[r][c];
        hv[c] = hh;
        lv[c] = (_Float16)(oa[r][c] - (float)hh);
      }
      *(h4*)(oh + ob + (size_t)(i0 + r) * 512) = hv;
      *(h4*)(ol + ob + (size_t)(i0 + r) * 512) = lv;
    }
}

// sb2[m] = dpb . emb[m]
__global__ __launch_bounds__(256) void sb2_k(
    const float* __restrict__ emb, const float* __restrict__ dpb, float* __restrict__ sb2)
{
  int m = blockIdx.x * 4 + (threadIdx.x >> 6);
  int lane = threadIdx.x & 63;
  const float* er = emb + (size_t)m * 512;
  float s = 0.f;
  for (int e = lane; e < 512; e += 64) s += dpb[e] * er[e];
  for (int msk = 32; msk; msk >>= 1) s += __shfl_xor(s, msk);
  if (lane == 0) sb2[m] = s;
}

// ---------------------------------------------------------------------------
// decode init: ctx planes = split(mean emb), h = 0 (fp32 + planes), state = 0,
// zero all barrier flags (arr 900*128 + rel 900 contiguous).
// ---------------------------------------------------------------------------
__global__ __launch_bounds__(256) void init_k(
    const float* __restrict__ emb, _Float16* __restrict__ ctxph, _Float16* __restrict__ ctxpl,
    float* __restrict__ ctxh, float* __restrict__ cbuf,
    int* visited, int* ucount, int* complete, int* allvis, int* first, int* prev,
    int* flags, float* out)
{
  int b = blockIdx.x, t = threadIdx.x;
#pragma unroll
  for (int r = 0; r < 2; ++r) {
    int e = t + 256 * r;
    float s = 0.f;
    for (int i = 0; i < Nn; ++i) s += emb[((size_t)b * Nn + i) * 512 + e];
    s *= (1.f / 100.f);
    _Float16 hh = (_Float16)s;
    ctxph[b * 1024 + e] = hh;
    ctxpl[b * 1024 + e] = (_Float16)(s - (float)hh);
    ctxph[b * 1024 + 512 + e] = (_Float16)0.f;
    ctxpl[b * 1024 + 512 + e] = (_Float16)0.f;
    ctxh[(size_t)b * 1024 + 512 + e] = 0.f;
    cbuf[(size_t)b * 512 + e] = 0.f;
  }
  if (t < Nn) visited[b * Nn + t] = 0;
  if (t == 0) {
    ucount[b] = 0; complete[b] = 0; allvis[b] = 0; first[b] = 0; prev[b] = 0;
    out[150 * Bb + b] = 0.f;
  }
  for (int i = b * 256 + t; i < 900 * NBLK + 900; i += 128 * 256) flags[i] = 0;
}

// ---------------------------------------------------------------------------
__device__ __forceinline__ float sigm(float x) { return 1.f / (1.f + expf(-x)); }

// Contention-free grid barrier: per-block arrival flags + single release flag.
__device__ __forceinline__ void gbar(int* arr, int* rel, int slot, int bid)
{
  __syncthreads();
  if (threadIdx.x == 0) {
    __threadfence();
    __hip_atomic_store(&arr[slot * NBLK + bid], 1, __ATOMIC_RELEASE, __HIP_MEMORY_SCOPE_AGENT);
  }
  if (bid == 0) {
    if (threadIdx.x < 64) {
      int i0 = slot * NBLK + threadIdx.x * 2;
      for (;;) {
        int a0 = __hip_atomic_load(&arr[i0], __ATOMIC_ACQUIRE, __HIP_MEMORY_SCOPE_AGENT);
        int a1 = __hip_atomic_load(&arr[i0 + 1], __ATOMIC_ACQUIRE, __HIP_MEMORY_SCOPE_AGENT);
        if (__all(a0 && a1)) break;
      }
    }
    __syncthreads();
    if (threadIdx.x == 0) {
      __threadfence();
      __hip_atomic_store(&rel[slot], 1, __ATOMIC_RELEASE, __HIP_MEMORY_SCOPE_AGENT);
    }
  } else {
    if (threadIdx.x == 0) {
      while (__hip_atomic_load(&rel[slot], __ATOMIC_ACQUIRE, __HIP_MEMORY_SCOPE_AGENT) == 0) {}
      __threadfence();
    }
  }
  __syncthreads();
}

// split-f16 MFMA tile for gates (port of passing mgemm_k, m0=0, partial out)
__device__ __forceinline__ void mfma_tile(
    const _Float16* __restrict__ Ah, const _Float16* __restrict__ Al, int lda,
    const _Float16* __restrict__ Bh, const _Float16* __restrict__ Bl, int ldb,
    int n0, int k0, int kc, float* __restrict__ Pout, int ldc,
    char* smraw, int tid)
{
  _Float16* sAh = (_Float16*)smraw;
  _Float16* sAl = sAh + 5120;
  _Float16* sBh = sAl + 5120;
  _Float16* sBl = sBh + 5120;
  const int lane = tid & 63, wave = tid >> 6;
  const int wm = wave >> 1, wn = wave & 1;
  const int m16 = lane & 15, kg = lane >> 4;
  f4 acc[4][4];
#pragma unroll
  for (int i = 0; i < 4; ++i)
#pragma unroll
    for (int j = 0; j < 4; ++j) acc[i][j] = (f4)0.f;

  for (int kt = k0; kt < k0 + kc; kt += 32) {
#pragma unroll
    for (int it = 0; it < 2; ++it) {
      int idx = tid + it * 256;
      int row = idx >> 2, g = idx & 3;
      int lo_ = row * 40 + g * 8;
      size_t ga = (size_t)row * lda + kt + g * 8;
      size_t gb = (size_t)(n0 + row) * ldb + kt + g * 8;
      *(h8*)(sAh + lo_) = *(const h8*)(Ah + ga);
      *(h8*)(sAl + lo_) = *(const h8*)(Al + ga);
      *(h8*)(sBh + lo_) = *(const h8*)(Bh + gb);
      *(h8*)(sBl + lo_) = *(const h8*)(Bl + gb);
    }
    __syncthreads();
    h8 a_h[4], a_l[4], b_h[4], b_l[4];
#pragma unroll
    for (int i = 0; i < 4; ++i) {
      int ro = (wm * 64 + i * 16 + m16) * 40 + kg * 8;
      int co = (wn * 64 + i * 16 + m16) * 40 + kg * 8;
      a_h[i] = *(const h8*)(sAh + ro);
      a_l[i] = *(const h8*)(sAl + ro);
      b_h[i] = *(const h8*)(sBh + co);
      b_l[i] = *(const h8*)(sBl + co);
    }
#pragma unroll
    for (int i = 0; i < 4; ++i)
#pragma unroll
      for (int j = 0; j < 4; ++j) {
        acc[i][j] = __builtin_amdgcn_mfma_f32_16x16x32_f16(a_h[i], b_h[j], acc[i][j], 0, 0, 0);
        acc[i][j] = __builtin_amdgcn_mfma_f32_16x16x32_f16(a_h[i], b_l[j], acc[i][j], 0, 0, 0);
        acc[i][j] = __builtin_amdgcn_mfma_f32_16x16x32_f16(a_l[i], b_h[j], acc[i][j], 0, 0, 0);
      }
    __syncthreads();
  }
  int rb = wm * 64 + kg * 4;
  int cb = n0 + wn * 64 + m16;
#pragma unroll
  for (int j = 0; j < 4; ++j)
#pragma unroll
    for (int i = 0; i < 4; ++i)
#pragma unroll
      for (int r = 0; r < 4; ++r)
        Pout[(size_t)(rb + i * 16 + r) * ldc + cb + j * 16] = acc[i][j][r];
}

// round-2/4 fp32 gemm device fn (small decode GEMMs), virtual block ids
__device__ void gemm_dev(
    int bx, int by, int bz,
    const float* __restrict__ A, int lda,
    const float* __restrict__ B1, const float* __restrict__ B2, int splitB, int ldb,
    float* __restrict__ C, int ldc, int kChunk, char* smraw)
{
  float (*As)[36] = (float(*)[36])smraw;
  float (*Bs)[68] = (float(*)[68])(smraw + 2304);
  const int tid = threadIdx.x;
  const int m0 = by * 32, n0 = bx * 64;
  const int k0 = bz * kChunk, kEnd = k0 + kChunk;
  const int tm = tid >> 4, tn = tid & 15;
  float acc[2][4];
#pragma unroll
  for (int i = 0; i < 2; ++i)
#pragma unroll
    for (int j = 0; j < 4; ++j) acc[i][j] = 0.f;

  for (int kt = k0; kt < kEnd; kt += 16) {
    for (int c = tid; c < 128; c += 256) {
      int mm = c >> 2;
      int k4 = (c & 3) * 4;
      float4 av = *(const float4*)(A + (size_t)(m0 + mm) * lda + kt + k4);
      As[k4 + 0][mm] = av.x;
      As[k4 + 1][mm] = av.y;
      As[k4 + 2][mm] = av.z;
      As[k4 + 3][mm] = av.w;
    }
    for (int c = tid; c < 256; c += 256) {
      int kk = c >> 4;
      int n4 = (c & 15) * 4;
      int kgi = kt + kk;
      const float* Brow = (kgi < splitB) ? (B1 + (size_t)kgi * ldb)
                                         : (B2 + (size_t)(kgi - splitB) * ldb);
      *(float4*)&Bs[kk][n4] = *(const float4*)(Brow + n0 + n4);
    }
    __syncthreads();
#pragma unroll
    for (int kk = 0; kk < 16; ++kk) {
      float a[2], b[4];
#pragma unroll
      for (int i = 0; i < 2; ++i) a[i] = As[kk][tm * 2 + i];
#pragma unroll
      for (int j = 0; j < 4; ++j) b[j] = Bs[kk][tn * 4 + j];
#pragma unroll
      for (int i = 0; i < 2; ++i)
#pragma unroll
        for (int j = 0; j < 4; ++j)
          acc[i][j] += a[i] * b[j];
    }
    __syncthreads();
  }

  float* Cout = C + (size_t)bz * 128 * ldc;
#pragma unroll
  for (int i = 0; i < 2; ++i) {
    int m = m0 + tm * 2 + i;
    int n = n0 + tn * 4;
    float4 r;
    r.x = acc[i][0]; r.y = acc[i][1]; r.z = acc[i][2]; r.w = acc[i][3];
    *(float4*)(Cout + (size_t)m * ldc + n) = r;
  }
}

struct DP {
  const _Float16 *WgTh, *WgTl;       // [2048][1024] gates weight planes
  const float *bih, *bhh;
  const float *dwq, *dbq, *dwo, *dbo, *dlng, *dlnb;
  const float *done_w, *done_b;
  const _Float16 *embh, *embl;       // node_emb planes
  const float *Kd, *Vd;              // [12800][512]
  const float *M2;                   // [12800][512] = emb @ dpw^T
  const float *sb2;                  // [12800]    = dpb . emb
  const float *ew, *sbp, *rpp;
  _Float16 *ctxph, *ctxpl;           // [128][1024] planes of [ctx|h]
  float *ctxh;                       // [128][1024] fp32 (h half used)
  float *cbuf, *gatesP, *qP, *woP, *dbuf;
  int *visited, *ucount, *complete, *allvis, *first, *prev;
  int *arr, *rel;
  float *out;
};

__global__ __launch_bounds__(256, 1) void decode_pers_k(DP P)
{
  const int bid = blockIdx.x;
  const int t = threadIdx.x;
  __shared__ __align__(16) char smraw[40960];
  const int BIG = 1 << 30;

  for (int step = 0; step < STEPS; ++step) {
    const int s6 = step * 6;

    // ---- P1: gates GEMM partials, split-f16 MFMA (16 nchunk x 8 ksplit) ----
    {
      int nch = bid & 15, ks = bid >> 4;
      mfma_tile(P.ctxph, P.ctxpl, 1024, P.WgTh, P.WgTl, 1024,
                nch * 128, ks * 128, 128,
                P.gatesP + (size_t)ks * 262144, 2048, smraw, t);
    }
    gbar(P.arr, P.rel, s6 + 0, bid);

    // ---- P2: LSTM pointwise per b ----
    {
      int b = bid;
      float* red = (float*)smraw;
      float dsum = 0.f;
#pragma unroll
      for (int r = 0; r < 2; ++r) {
        int e = t + 256 * r;
        float gv[4];
#pragma unroll
        for (int gi = 0; gi < 4; ++gi) {
          int col = gi * 512 + e;
          float s = P.bih[col] + P.bhh[col];
#pragma unroll
          for (int z = 0; z < 8; ++z) s += P.gatesP[(size_t)z * 262144 + b * 2048 + col];
          gv[gi] = s;
        }
        float cprev = P.cbuf[(size_t)b * 512 + e];
        float c2 = sigm(gv[1]) * cprev + sigm(gv[0]) * tanhf(gv[2]);
        float h2 = sigm(gv[3]) * tanhf(c2);
        P.cbuf[(size_t)b * 512 + e] = c2;
        P.ctxh[(size_t)b * 1024 + 512 + e] = h2;
        _Float16 hh = (_Float16)h2;
        P.ctxph[b * 1024 + 512 + e] = hh;
        P.ctxpl[b * 1024 + 512 + e] = (_Float16)(h2 - (float)hh);
        dsum += h2 * P.done_w[e];
      }
      red[t] = dsum; __syncthreads();
      for (int o = 128; o > 0; o >>= 1) { if (t < o) red[t] += red[t + o]; __syncthreads(); }
      if (t == 0) {
        float z = red[0] + P.done_b[0];
        if (!P.complete[b] && P.ucount[b] >= Nn && step >= Nn && z > 0.f) P.complete[b] = 1;
      }
    }
    gbar(P.arr, P.rel, s6 + 1, bid);

    // ---- P3: q GEMM partials, fp32 (grid (8,4,8), kChunk 64) ----
#pragma unroll 1
    for (int v = 0; v < 2; ++v) {
      int vb = bid * 2 + v;
      gemm_dev(vb & 7, (vb >> 3) & 3, vb >> 5,
               P.ctxh + 512, 1024, P.dwq, P.dwq, BIG, 512,
               P.qP, 512, 64, smraw);
    }
    gbar(P.arr, P.rel, s6 + 2, bid);

    // ---- P4: decoder attention (2 half-blocks x 4 items) ----
    {
      int half = t >> 7, tl = t & 127;
      float* qh = (float*)smraw + half * 320;
      float* pv = qh + 64;
      float* red = pv + 128;
#pragma unroll 1
      for (int r4 = 0; r4 < 4; ++r4) {
        int item = bid * 8 + r4 * 2 + half;
        int b = item >> 3, h = item & 7;
        if (tl < 64) {
          float s = P.dbq[h * 64 + tl];
#pragma unroll
          for (int z = 0; z < 8; ++z) s += P.qP[(size_t)z * 65536 + (size_t)b * 512 + h * 64 + tl];
          qh[tl] = s;
        }
        __syncthreads();
        float scv = -3.4e38f;
        if (tl < Nn) {
          const float* kr = P.Kd + ((size_t)(b * Nn + tl)) * 512 + h * 64;
          float s = 0.f;
#pragma unroll
          for (int d = 0; d < 64; ++d) s += qh[d] * kr[d];
          scv = s * 0.125f;
        }
        red[tl] = scv; __syncthreads();
        for (int o2 = 64; o2 > 0; o2 >>= 1) { if (tl < o2) red[tl] = fmaxf(red[tl], red[tl + o2]); __syncthreads(); }
        float m = red[0]; __syncthreads();
        float ex = (tl < Nn) ? expf(scv - m) : 0.f;
        red[tl] = ex; __syncthreads();
        for (int o2 = 64; o2 > 0; o2 >>= 1) { if (tl < o2) red[tl] += red[tl + o2]; __syncthreads(); }
        float Z = red[0];
        if (tl < Nn) pv[tl] = ex / Z;
        __syncthreads();
        if (tl < 64) {
          float acc = 0.f;
          const float* vr = P.Vd + (size_t)(b * Nn) * 512 + h * 64 + tl;
          for (int j = 0; j < Nn; ++j) acc += pv[j] * vr[(size_t)j * 512];
          P.dbuf[(size_t)b * 512 + h * 64 + tl] = acc;
        }
        __syncthreads();
      }
    }
    gbar(P.arr, P.rel, s6 + 3, bid);

    // ---- P5: wo GEMM partials, fp32 ----
#pragma unroll 1
    for (int v = 0; v < 2; ++v) {
      int vb = bid * 2 + v;
      gemm_dev(vb & 7, (vb >> 3) & 3, vb >> 5,
               P.dbuf, 512, P.dwo, P.dwo, BIG, 512,
               P.woP, 512, 64, smraw);
    }
    gbar(P.arr, P.rel, s6 + 4, bid);

    // ---- P6: LN + M2-scores + select per b ----
    {
      int b = bid;
      float* av = (float*)smraw;            // 512
      float* red = av + 512;                // 256
      int* redi = (int*)(red + 256);        // 256
      float* sc = (float*)(redi + 256);     // 128
      float v[2];
#pragma unroll
      for (int r = 0; r < 2; ++r) {
        int e = t + 256 * r;
        float s = P.dbo[e];
#pragma unroll
        for (int z = 0; z < 8; ++z) s += P.woP[(size_t)z * 65536 + (size_t)b * 512 + e];
        v[r] = s;
      }
      red[t] = v[0] + v[1]; __syncthreads();
      for (int o = 128; o > 0; o >>= 1) { if (t < o) red[t] += red[t + o]; __syncthreads(); }
      float mu = red[0] * (1.f / 512.f);
      __syncthreads();
      float d0 = v[0] - mu, d1 = v[1] - mu;
      red[t] = d0 * d0 + d1 * d1; __syncthreads();
      for (int o = 128; o > 0; o >>= 1) { if (t < o) red[t] += red[t + o]; __syncthreads(); }
      float inv = 1.f / sqrtf(red[0] * (1.f / 512.f) + 1e-5f);
      av[t] = d0 * inv * P.dlng[t] + P.dlnb[t];
      av[t + 256] = d1 * inv * P.dlng[t + 256] + P.dlnb[t + 256];
      __syncthreads();
      if (t < Nn) {
        const float* m2r = P.M2 + ((size_t)(b * Nn + t)) * 512;
        float s = P.sb2[b * Nn + t];
        for (int j = 0; j < 512; ++j) s += av[j] * m2r[j];
        int avz = P.allvis[b];
        if (!avz && P.visited[b * Nn + t]) s = P.rpp[0];
        if (avz) {
          int pvn = P.prev[b];
          float direct = P.ew[(size_t)b * 10000 + (size_t)pvn * 100];
          float via = P.ew[(size_t)b * 10000 + (size_t)pvn * 100 + t]
                    + P.ew[(size_t)b * 10000 + (size_t)t * 100];
          if (via < direct) s += P.sbp[0] * (direct - via) / direct;
        }
        if (P.complete[b]) s = (t == P.first[b]) ? 100.f : -1e9f;
        sc[t] = s;
      }
      __syncthreads();
      float vv = (t < Nn) ? sc[t] : -3.4e38f;
      int ii = (t < Nn) ? t : 0x7fffffff;
      red[t] = vv; redi[t] = ii;
      __syncthreads();
      for (int o = 128; o > 0; o >>= 1) {
        if (t < o) {
          float v2 = red[t + o]; int i2 = redi[t + o];
          if (v2 > red[t] || (v2 == red[t] && i2 < redi[t])) { red[t] = v2; redi[t] = i2; }
        }
        __syncthreads();
      }
      float m = red[0];
      int curr = redi[0];
      __syncthreads();
      float ex = (t < Nn) ? expf(sc[t] - m) : 0.f;
      red[t] = ex; __syncthreads();
      for (int o = 128; o > 0; o >>= 1) { if (t < o) red[t] += red[t + o]; __syncthreads(); }
      float Z = red[0];
      if (t == 0) {
        float pcur = expf(sc[curr] - m) / Z;
        P.out[step * Bb + b] = logf(pcur + 1e-10f);
        P.out[(151 + step) * Bb + b] = (float)curr;
        if (!P.complete[b]) {
          if (!P.visited[b * Nn + curr]) P.ucount[b] = P.ucount[b] + 1;
          P.visited[b * Nn + curr] = 1;
        }
        if (P.ucount[b] >= Nn) P.allvis[b] = 1;
        if (step == 0) P.first[b] = curr;
        P.prev[b] = curr;
      }
      size_t src = ((size_t)(b * Nn) + (size_t)redi[0]) * 512;
      P.ctxph[b * 1024 + t]       = P.embh[src + t];
      P.ctxph[b * 1024 + t + 256] = P.embh[src + t + 256];
      P.ctxpl[b * 1024 + t]       = P.embl[src + t];
      P.ctxpl[b * 1024 + t + 256] = P.embl[src + t + 256];
    }
    gbar(P.arr, P.rel, s6 + 5, bid);
  }

  if (bid == 0 && t < 128)
    P.out[(151 + 150) * Bb + t] = P.complete[t] ? 0.f : (float)P.first[t];
}

// ---------------------------------------------------------------------------
extern "C" void kernel_launch(void* const* d_in, const int* in_sizes, int n_in,
                              void* d_out, int out_size, void* d_ws, size_t ws_size,
                              hipStream_t stream)
{
  const float* nf      = (const float*)d_in[0];
  const float* ew      = (const float*)d_in[1];
  const float* pe      = (const float*)d_in[2];
  const float* in_w    = (const float*)d_in[3];
  const float* in_b    = (const float*)d_in[4];
  const float* enc_wq  = (const float*)d_in[5];
  const float* enc_wk  = (const float*)d_in[6];
  const float* enc_wv  = (const float*)d_in[7];
  const float* enc_wo  = (const float*)d_in[8];
  const float* enc_bq  = (const float*)d_in[9];
  const float* enc_bk  = (const float*)d_in[10];
  const float* enc_bv  = (const float*)d_in[11];
  const float* enc_bo  = (const float*)d_in[12];
  const float* enc_w1  = (const float*)d_in[13];
  const float* enc_b1  = (const float*)d_in[14];
  const float* enc_w2  = (const float*)d_in[15];
  const float* enc_b2  = (const float*)d_in[16];
  const float* ln1g    = (const float*)d_in[17];
  const float* ln1b    = (const float*)d_in[18];
  const float* ln2g    = (const float*)d_in[19];
  const float* ln2b    = (const float*)d_in[20];
  const float* wih     = (const float*)d_in[21];
  const float* whh     = (const float*)d_in[22];
  const float* bih     = (const float*)d_in[23];
  const float* bhh     = (const float*)d_in[24];
  const float* dwq     = (const float*)d_in[25];
  const float* dwk     = (const float*)d_in[26];
  const float* dwv     = (const float*)d_in[27];
  const float* dwo     = (const float*)d_in[28];
  const float* dpw     = (const float*)d_in[29];
  const float* dbq     = (const float*)d_in[30];
  const float* dbk     = (const float*)d_in[31];
  const float* dbv     = (const float*)d_in[32];
  const float* dbo     = (const float*)d_in[33];
  const float* dpb     = (const float*)d_in[34];
  const float* dlng    = (const float*)d_in[35];
  const float* dlnb    = (const float*)d_in[36];
  const float* sbp     = (const float*)d_in[37];
  const float* rpp     = (const float*)d_in[38];
  const float* done_w  = (const float*)d_in[39];
  const float* done_b  = (const float*)d_in[40];
  float* out = (float*)d_out;

  // ---- workspace carve ----
  const size_t SZ = 12800ull * 512;
  float* ws = (float*)d_ws;
  float* x   = ws;
  float* xq  = x + SZ;                          // enc scratch -> M2
  float* xk  = xq + SZ;                         // enc k -> dec K
  float* xv  = xk + SZ;                         // enc v / ff2 partials -> dec V
  _Float16* xh = (_Float16*)(xv + SZ);          // node_emb planes (persist into decode)
  _Float16* xl = xh + SZ;
  _Float16* oh = xl + SZ;                       // enc scratch planes -> decode region
  _Float16* ol = oh + SZ;
  _Float16* wb = ol + SZ;                       // encoder weight planes
  _Float16* wqh = wb;               _Float16* wql = wqh + 262144;
  _Float16* wkh = wql + 262144;     _Float16* wkl = wkh + 262144;
  _Float16* wvh = wkl + 262144;     _Float16* wvl = wvh + 262144;
  _Float16* woh_ = wvl + 262144;    _Float16* wol_ = woh_ + 262144;
  _Float16* w1h = wol_ + 262144;    _Float16* w1l = w1h + 1048576;
  _Float16* w2h = w1l + 1048576;    _Float16* w2l = w2h + 1048576;
  // tail: sb2 + state + barrier flags
  float* sb2    = (float*)(w2l + 1048576);      // 12800 f
  int* ivis     = (int*)(sb2 + 12800);          // 128*100
  int* ucount   = ivis + 12800;
  int* complete = ucount + 128;
  int* allvis   = complete + 128;
  int* first    = allvis + 128;
  int* prev     = first + 128;
  int* arr      = prev + 128;                   // 900*128
  int* rel      = arr + 900 * NBLK;             // 900 (contiguous after arr)
  // decode-persistent buffers inside oh/ol (free after encoder)
  _Float16* WgTh = oh;                          // 2,097,152
  _Float16* WgTl = WgTh + 2097152;
  _Float16* dpwNh = WgTl + 2097152;             // 262,144
  _Float16* dpwNl = dpwNh + 262144;
  _Float16* ctxph = dpwNl + 262144;             // 131,072
  _Float16* ctxpl = ctxph + 131072;
  float* gatesP = (float*)(ctxpl + 131072);     // 8*128*2048
  float* qP     = gatesP + 2097152;             // 8*128*512
  float* woP    = qP + 524288;                  // 8*128*512
  float* ctxh   = woP + 524288;                 // 128*1024 (h half used)
  float* cbuf   = ctxh + 131072;                // 128*512
  float* dbuf   = cbuf + 65536;                 // 128*512
  float* M2 = xq;

  // ---- encoder (round-2/4, unchanged) ----
  input_proj_k<<<25600, 256, 0, stream>>>(nf, in_w, in_b, pe, x, xh, xl);

  for (int l = 0; l < Ll; ++l) {
    const float* wq = enc_wq + (size_t)l * 262144;
    const float* wk = enc_wk + (size_t)l * 262144;
    const float* wv = enc_wv + (size_t)l * 262144;
    const float* wo = enc_wo + (size_t)l * 262144;
    const float* bq = enc_bq + (size_t)l * 512;
    const float* bk = enc_bk + (size_t)l * 512;
    const float* bv = enc_bv + (size_t)l * 512;
    const float* bo = enc_bo + (size_t)l * 512;
    const float* w1 = enc_w1 + (size_t)l * 1048576;
    const float* b1 = enc_b1 + (size_t)l * 2048;
    const float* w2 = enc_w2 + (size_t)l * 1048576;
    const float* b2 = enc_b2 + (size_t)l * 512;

    wconv_k<<<dim3(16, 16), 256, 0, stream>>>(wq, 512, 512, wqh, wql);
    wconv_k<<<dim3(16, 16), 256, 0, stream>>>(wk, 512, 512, wkh, wkl);
    wconv_k<<<dim3(16, 16), 256, 0, stream>>>(wv, 512, 512, wvh, wvl);
    wconv_k<<<dim3(16, 16), 256, 0, stream>>>(wo, 512, 512, woh_, wol_);
    wconv_k<<<dim3(64, 16), 256, 0, stream>>>(w1, 512, 2048, w1h, w1l);
    wconv_k<<<dim3(16, 64), 256, 0, stream>>>(w2, 2048, 512, w2h, w2l);

    // NOTE: attn-out / FF1 planes use oh/ol as scratch during encoder only.
    mgemm_k<false, true, true, false><<<dim3(4, 100), 256, 0, stream>>>(
        xh, xl, 512, wqh, wql, 512, xq, nullptr, nullptr, 512, bq, 512, 0, 0);
    mgemm_k<false, true, true, false><<<dim3(4, 100), 256, 0, stream>>>(
        xh, xl, 512, wkh, wkl, 512, xk, nullptr, nullptr, 512, bk, 512, 0, 0);
    mgemm_k<false, true, true, false><<<dim3(4, 100), 256, 0, stream>>>(
        xh, xl, 512, wvh, wvl, 512, xv, nullptr, nullptr, 512, bv, 512, 0, 0);
    enc_attn_k<<<1024, 256, 0, stream>>>(xq, xk, xv, oh, ol);
    mgemm_k<false, true, true, false><<<dim3(4, 100), 256, 0, stream>>>(
        oh, ol, 512, woh_, wol_, 512, xq, nullptr, nullptr, 512, bo, 512, 0, 0);
    ln_k<<<12800, 256, 0, stream>>>(x, xq, ln1g + l * 512, ln1b + l * 512, x, xh, xl);
    for (int c = 0; c < 4; ++c) {
      mgemm_k<true, true, false, false><<<dim3(16, 25), 256, 0, stream>>>(
          xh + (size_t)c * 3200 * 512, xl + (size_t)c * 3200 * 512, 512,
          w1h, w1l, 512, nullptr, oh, ol, 2048, b1, 512, 0, 0);
      mgemm_k<false, false, true, true><<<dim3(4, 25, 4), 256, 0, stream>>>(
          oh, ol, 2048, w2h, w2l, 2048, xv, nullptr, nullptr, 512,
          nullptr, 2048, 512, 3200);
      reduce4_k<<<6400, 256, 0, stream>>>(xv, b2, xq + (size_t)c * 3200 * 512);
    }
    ln_k<<<12800, 256, 0, stream>>>(x, xq, ln2g + l * 512, ln2b + l * 512, x, xh, xl);
  }

  // ---- decode prep ----
  wconv_k<<<dim3(16, 16), 256, 0, stream>>>(dwk, 512, 512, wqh, wql);
  wconv_k<<<dim3(16, 16), 256, 0, stream>>>(dwv, 512, 512, wkh, wkl);
  mgemm_k<false, true, true, false><<<dim3(4, 100), 256, 0, stream>>>(
      xh, xl, 512, wqh, wql, 512, xk, nullptr, nullptr, 512, dbk, 512, 0, 0);
  mgemm_k<false, true, true, false><<<dim3(4, 100), 256, 0, stream>>>(
      xh, xl, 512, wkh, wkl, 512, xv, nullptr, nullptr, 512, dbv, 512, 0, 0);
  wconv2_k<<<dim3(64, 32), 256, 0, stream>>>(wih, whh, 2048, WgTh, WgTl);
  wsplit_k<<<1024, 256, 0, stream>>>(dpw, dpwNh, dpwNl, 262144);
  mgemm_k<false, false, true, false><<<dim3(4, 100), 256, 0, stream>>>(
      xh, xl, 512, dpwNh, dpwNl, 512, M2, nullptr, nullptr, 512, nullptr, 512, 0, 0);
  sb2_k<<<3200, 256, 0, stream>>>(x, dpb, sb2);
  init_k<<<128, 256, 0, stream>>>(x, ctxph, ctxpl, ctxh, cbuf, ivis, ucount, complete,
                                  allvis, first, prev, arr, out);

  // ---- persistent decode (one normal launch) ----
  DP p;
  p.WgTh = WgTh; p.WgTl = WgTl;
  p.bih = bih; p.bhh = bhh;
  p.dwq = dwq; p.dbq = dbq; p.dwo = dwo; p.dbo = dbo;
  p.dlng = dlng; p.dlnb = dlnb;
  p.done_w = done_w; p.done_b = done_b;
  p.embh = xh; p.embl = xl;
  p.Kd = xk; p.Vd = xv; p.M2 = M2; p.sb2 = sb2;
  p.ew = ew; p.sbp = sbp; p.rpp = rpp;
  p.ctxph = ctxph; p.ctxpl = ctxpl; p.ctxh = ctxh;
  p.cbuf = cbuf; p.gatesP = gatesP; p.qP = qP; p.woP = woP; p.dbuf = dbuf;
  p.visited = ivis; p.ucount = ucount; p.complete = complete;
  p.allvis = allvis; p.first = first; p.prev = prev;
  p.arr = arr; p.rel = rel;
  p.out = out;
  decode_pers_k<<<NBLK, 256, 0, stream>>>(p);
}

// Round 6
// 21286.136 us; speedup vs baseline: 2.0436x; 2.0436x over previous
//
#include <hip/hip_runtime.h>
#include <math.h>

#define Bb 128
#define Nn 100
#define Ee 512
#define Hh 8
#define DHd 64
#define FFf 2048
#define Ll 6
#define STEPS 150

typedef _Float16 h8 __attribute__((ext_vector_type(8)));
typedef _Float16 h4 __attribute__((ext_vector_type(4)));
typedef float f4 __attribute__((ext_vector_type(4)));

// ---------------------------------------------------------------------------
// Split-f16 MFMA GEMM (encoder + prep).  C = A@B via Ah*Bh + Ah*Bl + Al*Bh.
// A planes [M][K] f16, B planes pre-transposed [N][K] f16.  (proven r2)
// ---------------------------------------------------------------------------
template<bool RELU, bool BIAS, bool OUTF32, bool SPLITK>
__global__ __launch_bounds__(256) void mgemm_k(
    const _Float16* __restrict__ Ah, const _Float16* __restrict__ Al, int lda,
    const _Float16* __restrict__ Bh, const _Float16* __restrict__ Bl, int ldb,
    float* __restrict__ C, _Float16* __restrict__ Ch, _Float16* __restrict__ Cl,
    int ldc, const float* __restrict__ bias, int K, int kc, int Mtot)
{
  __shared__ _Float16 sm[4 * 5120];
  _Float16* sAh = sm;
  _Float16* sAl = sm + 5120;
  _Float16* sBh = sm + 10240;
  _Float16* sBl = sm + 15360;
  const int tid = threadIdx.x;
  const int m0 = blockIdx.y * 128, n0 = blockIdx.x * 128;
  const int k0 = SPLITK ? blockIdx.z * kc : 0;
  const int kEnd = SPLITK ? (k0 + kc) : K;
  const int lane = tid & 63, wave = tid >> 6;
  const int wm = wave >> 1, wn = wave & 1;
  const int m16 = lane & 15, kg = lane >> 4;
  f4 acc[4][4];
#pragma unroll
  for (int i = 0; i < 4; ++i)
#pragma unroll
    for (int j = 0; j < 4; ++j) acc[i][j] = (f4)0.f;

  for (int kt = k0; kt < kEnd; kt += 32) {
#pragma unroll
    for (int it = 0; it < 2; ++it) {
      int idx = tid + it * 256;
      int row = idx >> 2, g = idx & 3;
      int lo_ = row * 40 + g * 8;
      size_t ga = (size_t)(m0 + row) * lda + kt + g * 8;
      size_t gb = (size_t)(n0 + row) * ldb + kt + g * 8;
      *(h8*)(sAh + lo_) = *(const h8*)(Ah + ga);
      *(h8*)(sAl + lo_) = *(const h8*)(Al + ga);
      *(h8*)(sBh + lo_) = *(const h8*)(Bh + gb);
      *(h8*)(sBl + lo_) = *(const h8*)(Bl + gb);
    }
    __syncthreads();
    h8 a_h[4], a_l[4], b_h[4], b_l[4];
#pragma unroll
    for (int i = 0; i < 4; ++i) {
      int ro = (wm * 64 + i * 16 + m16) * 40 + kg * 8;
      int co = (wn * 64 + i * 16 + m16) * 40 + kg * 8;
      a_h[i] = *(const h8*)(sAh + ro);
      a_l[i] = *(const h8*)(sAl + ro);
      b_h[i] = *(const h8*)(sBh + co);
      b_l[i] = *(const h8*)(sBl + co);
    }
#pragma unroll
    for (int i = 0; i < 4; ++i)
#pragma unroll
      for (int j = 0; j < 4; ++j) {
        acc[i][j] = __builtin_amdgcn_mfma_f32_16x16x32_f16(a_h[i], b_h[j], acc[i][j], 0, 0, 0);
        acc[i][j] = __builtin_amdgcn_mfma_f32_16x16x32_f16(a_h[i], b_l[j], acc[i][j], 0, 0, 0);
        acc[i][j] = __builtin_amdgcn_mfma_f32_16x16x32_f16(a_l[i], b_h[j], acc[i][j], 0, 0, 0);
      }
    __syncthreads();
  }

  float* Cz = OUTF32 ? (C + (SPLITK ? (size_t)blockIdx.z * (size_t)Mtot * ldc : (size_t)0)) : C;
  int rb = m0 + wm * 64 + kg * 4;
  int cb = n0 + wn * 64 + m16;
#pragma unroll
  for (int j = 0; j < 4; ++j) {
    int col = cb + j * 16;
    float bv = BIAS ? bias[col] : 0.f;
#pragma unroll
    for (int i = 0; i < 4; ++i) {
#pragma unroll
      for (int r = 0; r < 4; ++r) {
        float v = acc[i][j][r] + bv;
        if (RELU) v = fmaxf(v, 0.f);
        int row = rb + i * 16 + r;
        if (OUTF32) {
          Cz[(size_t)row * ldc + col] = v;
        } else {
          _Float16 hh = (_Float16)v;
          Ch[(size_t)row * ldc + col] = hh;
          Cl[(size_t)row * ldc + col] = (_Float16)(v - (float)hh);
        }
      }
    }
  }
}

// ---------------------------------------------------------------------------
// Weight transpose + split:  W [K][N] fp32 -> Th/Tl [N][K] f16   (proven)
// ---------------------------------------------------------------------------
__global__ __launch_bounds__(256) void wconv_k(
    const float* __restrict__ W, int K, int N,
    _Float16* __restrict__ Th, _Float16* __restrict__ Tl)
{
  __shared__ float t[32][33];
  int n0 = blockIdx.x * 32, k0 = blockIdx.y * 32;
  int tid = threadIdx.x;
  int r = tid >> 3, c4 = (tid & 7) * 4;
  float4 v = *(const float4*)(W + (size_t)(k0 + r) * N + n0 + c4);
  t[r][c4 + 0] = v.x; t[r][c4 + 1] = v.y; t[r][c4 + 2] = v.z; t[r][c4 + 3] = v.w;
  __syncthreads();
  h4 hi, lo;
#pragma unroll
  for (int i = 0; i < 4; ++i) {
    float x = t[c4 + i][r];
    _Float16 hh = (_Float16)x;
    hi[i] = hh;
    lo[i] = (_Float16)(x - (float)hh);
  }
  *(h4*)(Th + (size_t)(n0 + r) * K + k0 + c4) = hi;
  *(h4*)(Tl + (size_t)(n0 + r) * K + k0 + c4) = lo;
}

// Permuted gates weight: WgTperm row n' = j*16 + q*4 + r  <- orig col q*512+j*4+r
// of stacked [wih; whh] (K=1024).  One block per n' (2048 blocks).
__global__ __launch_bounds__(256) void wconvg_k(
    const float* __restrict__ Wa, const float* __restrict__ Wb,
    _Float16* __restrict__ Th, _Float16* __restrict__ Tl)
{
  int np = blockIdx.x;
  int j = np >> 4, q = (np >> 2) & 3, r = np & 3;
  int n = q * 512 + j * 4 + r;
  int t = threadIdx.x;
#pragma unroll
  for (int kk = 0; kk < 4; ++kk) {
    int k = t + kk * 256;
    float x = (k < 512) ? Wa[(size_t)k * 2048 + n] : Wb[(size_t)(k - 512) * 2048 + n];
    _Float16 hh = (_Float16)x;
    Th[(size_t)np * 1024 + k] = hh;
    Tl[(size_t)np * 1024 + k] = (_Float16)(x - (float)hh);
  }
}

// plain elementwise split
__global__ __launch_bounds__(256) void wsplit_k(
    const float* __restrict__ W, _Float16* __restrict__ Th, _Float16* __restrict__ Tl, int n)
{
  int i = blockIdx.x * 256 + threadIdx.x;
  if (i < n) {
    float x = W[i];
    _Float16 hh = (_Float16)x;
    Th[i] = hh;
    Tl[i] = (_Float16)(x - (float)hh);
  }
}

// FF2 split-K(4) partial reduce + bias
__global__ __launch_bounds__(256) void reduce4_k(
    const float* __restrict__ P, const float* __restrict__ bias, float* __restrict__ out)
{
  int idx = blockIdx.x * 256 + threadIdx.x;
  const size_t S = 3200ull * 512;
  float v = P[idx] + P[idx + S] + P[idx + 2 * S] + P[idx + 3 * S] + bias[idx & 511];
  out[idx] = v;
}

// ---------------------------------------------------------------------------
__global__ __launch_bounds__(256) void input_proj_k(
    const float* __restrict__ nf, const float* __restrict__ inw,
    const float* __restrict__ inb, const float* __restrict__ pe,
    float* __restrict__ x, _Float16* __restrict__ xh, _Float16* __restrict__ xl)
{
  int idx = blockIdx.x * 256 + threadIdx.x;
  int bn = idx >> 9, e = idx & 511;
  int n = bn - (bn / Nn) * Nn;
  const float* fr = nf + (size_t)bn * 8;
  float s = inb[e] + pe[(size_t)n * 512 + e];
#pragma unroll
  for (int i = 0; i < 8; ++i) s += fr[i] * inw[(size_t)i * 512 + e];
  x[idx] = s;
  _Float16 hh = (_Float16)s;
  xh[idx] = hh;
  xl[idx] = (_Float16)(s - (float)hh);
}

__global__ __launch_bounds__(256) void ln_k(
    const float* __restrict__ xin, const float* __restrict__ yin,
    const float* __restrict__ g, const float* __restrict__ bb,
    float* __restrict__ out, _Float16* __restrict__ oh, _Float16* __restrict__ ol)
{
  int row = blockIdx.x, t = threadIdx.x;
  __shared__ float red[256];
  size_t base = (size_t)row * 512;
  float v0 = xin[base + t] + yin[base + t];
  float v1 = xin[base + 256 + t] + yin[base + 256 + t];
  red[t] = v0 + v1;
  __syncthreads();
  for (int o = 128; o > 0; o >>= 1) { if (t < o) red[t] += red[t + o]; __syncthreads(); }
  float mu = red[0] * (1.f / 512.f);
  __syncthreads();
  float d0 = v0 - mu, d1 = v1 - mu;
  red[t] = d0 * d0 + d1 * d1;
  __syncthreads();
  for (int o = 128; o > 0; o >>= 1) { if (t < o) red[t] += red[t + o]; __syncthreads(); }
  float inv = 1.f / sqrtf(red[0] * (1.f / 512.f) + 1e-5f);
  float y0 = d0 * inv * g[t] + bb[t];
  float y1 = d1 * inv * g[t + 256] + bb[t + 256];
  out[base + t] = y0;
  out[base + 256 + t] = y1;
  _Float16 h0 = (_Float16)y0, h1 = (_Float16)y1;
  oh[base + t] = h0;           ol[base + t] = (_Float16)(y0 - (float)h0);
  oh[base + 256 + t] = h1;     ol[base + 256 + t] = (_Float16)(y1 - (float)h1);
}

// ---------------------------------------------------------------------------
__global__ __launch_bounds__(256) void enc_attn_k(
    const float* __restrict__ q, const float* __restrict__ k,
    const float* __restrict__ v, _Float16* __restrict__ oh, _Float16* __restrict__ ol)
{
  __shared__ __align__(16) float smem[14848];
  int bh = blockIdx.x; int b = bh >> 3, h = bh & 7;
  int t = threadIdx.x;
  float* qs = smem;
  float* kT = smem + 7616;
  float* p  = smem;
  const float* qg = q + ((size_t)b * Nn) * 512 + h * 64;
  const float* kg = k + ((size_t)b * Nn) * 512 + h * 64;
  const float* vg = v + ((size_t)b * Nn) * 512 + h * 64;
  for (int idx = t; idx < 6400; idx += 256) {
    int i = idx >> 6, d = idx & 63;
    qs[i * 68 + d]  = qg[(size_t)i * 512 + d];
    kT[d * 113 + i] = kg[(size_t)i * 512 + d];
  }
  __syncthreads();
  int ti = t >> 4, tj = t & 15;
  int i0 = ti * 7, j0 = tj * 7;
  float s[7][7];
#pragma unroll
  for (int r = 0; r < 7; ++r)
#pragma unroll
    for (int c = 0; c < 7; ++c) s[r][c] = 0.f;
  for (int kk = 0; kk < 64; ++kk) {
    float a[7], bb[7];
#pragma unroll
    for (int r = 0; r < 7; ++r) a[r] = qs[(i0 + r) * 68 + kk];
#pragma unroll
    for (int c = 0; c < 7; ++c) bb[c] = kT[kk * 113 + j0 + c];
#pragma unroll
    for (int r = 0; r < 7; ++r)
#pragma unroll
      for (int c = 0; c < 7; ++c) s[r][c] += a[r] * bb[c];
  }
  __syncthreads();
#pragma unroll
  for (int r = 0; r < 7; ++r)
#pragma unroll
    for (int c = 0; c < 7; ++c) {
      int i = i0 + r, j = j0 + c;
      if (i < Nn && j < Nn) p[i * 104 + j] = s[r][c] * 0.125f;
    }
  __syncthreads();
  int w = t >> 6, lane = t & 63;
  for (int i = w; i < Nn; i += 4) {
    float x0 = p[i * 104 + lane];
    float x1 = (lane < 36) ? p[i * 104 + 64 + lane] : -3.4e38f;
    float mx = fmaxf(x0, x1);
    for (int msk = 32; msk; msk >>= 1) mx = fmaxf(mx, __shfl_xor(mx, msk));
    float e0 = expf(x0 - mx);
    float e1 = (lane < 36) ? expf(x1 - mx) : 0.f;
    float ss = e0 + e1;
    for (int msk = 32; msk; msk >>= 1) ss += __shfl_xor(ss, msk);
    p[i * 104 + lane] = e0 / ss;
    if (lane < 36) p[i * 104 + 64 + lane] = e1 / ss;
  }
  __syncthreads();
  int d0 = tj * 4;
  float oa[7][4];
#pragma unroll
  for (int r = 0; r < 7; ++r)
#pragma unroll
    for (int c = 0; c < 4; ++c) oa[r][c] = 0.f;
  for (int j = 0; j < Nn; ++j) {
    float pr[7];
#pragma unroll
    for (int r = 0; r < 7; ++r) pr[r] = p[(i0 + r) * 104 + j];
    float4 vv = *(const float4*)(vg + (size_t)j * 512 + d0);
#pragma unroll
    for (int r = 0; r < 7; ++r) {
      oa[r][0] += pr[r] * vv.x; oa[r][1] += pr[r] * vv.y;
      oa[r][2] += pr[r] * vv.z; oa[r][3] += pr[r] * vv.w;
    }
  }
  size_t ob = ((size_t)b * Nn) * 512 + h * 64 + d0;
#pragma unroll
  for (int r = 0; r < 7; ++r)
    if (i0 + r < Nn) {
      h4 hv, lv;
#pragma unroll
      for (int c = 0; c < 4; ++c) {
        _Float16 hh = (_Float16)oa[r][c];
        hv[c] = hh;
        lv[c] = (_Float16)(oa[r][c] - (float)hh);
      }
      *(h4*)(oh + ob + (size_t)(i0 + r) * 512) = hv;
      *(h4*)(ol + ob + (size_t)(i0 + r) * 512) = lv;
    }
}

// sb2[m] = dpb . emb[m]
__global__ __launch_bounds__(256) void sb2_k(
    const float* __restrict__ emb, const float* __restrict__ dpb, float* __restrict__ sb2)
{
  int m = blockIdx.x * 4 + (threadIdx.x >> 6);
  int lane = threadIdx.x & 63;
  const float* er = emb + (size_t)m * 512;
  float s = 0.f;
  for (int e = lane; e < 512; e += 64) s += dpb[e] * er[e];
  for (int msk = 32; msk; msk >>= 1) s += __shfl_xor(s, msk);
  if (lane == 0) sb2[m] = s;
}

// decode init
__global__ __launch_bounds__(256) void init2_k(
    const float* __restrict__ emb, _Float16* __restrict__ ctxph, _Float16* __restrict__ ctxpl,
    float* __restrict__ ctxh, float* __restrict__ cbuf,
    int* visited, int* ucount, int* complete, int* allvis, int* first, int* prev,
    float* out)
{
  int b = blockIdx.x, t = threadIdx.x;
#pragma unroll
  for (int r = 0; r < 2; ++r) {
    int e = t + 256 * r;
    float s = 0.f;
    for (int i = 0; i < Nn; ++i) s += emb[((size_t)b * Nn + i) * 512 + e];
    s *= (1.f / 100.f);
    _Float16 hh = (_Float16)s;
    ctxph[b * 1024 + e] = hh;
    ctxpl[b * 1024 + e] = (_Float16)(s - (float)hh);
    ctxph[b * 1024 + 512 + e] = (_Float16)0.f;
    ctxpl[b * 1024 + 512 + e] = (_Float16)0.f;
    ctxh[(size_t)b * 1024 + 512 + e] = 0.f;
    cbuf[(size_t)b * 512 + e] = 0.f;
  }
  if (t < Nn) visited[b * Nn + t] = 0;
  if (t == 0) {
    ucount[b] = 0; complete[b] = 0; allvis[b] = 0; first[b] = 0; prev[b] = 0;
    out[150 * Bb + b] = 0.f;
  }
}

// ---------------------------------------------------------------------------
__device__ __forceinline__ float sigm(float x) { return 1.f / (1.f + expf(-x)); }

// P1: gates MFMA (block j owns permuted cols j*16..j*16+16 = e-slice [4j,4j+4) x 4
// gates, full K=1024) + fused LSTM pointwise + h2 planes + done partial.
__global__ __launch_bounds__(256) void ph1_k(
    const _Float16* __restrict__ ctxph, const _Float16* __restrict__ ctxpl,
    const _Float16* __restrict__ WgTh, const _Float16* __restrict__ WgTl,
    const float* __restrict__ bih, const float* __restrict__ bhh,
    float* __restrict__ cbuf, float* __restrict__ ctxh,
    _Float16* __restrict__ hph, _Float16* __restrict__ hpl,
    const float* __restrict__ done_w, float* __restrict__ ddp)
{
  __shared__ __align__(16) _Float16 sm[11520];   // A hi/lo 2x5120, B hi/lo 2x640
  __shared__ __align__(16) float gt[128 * 17];
  _Float16* sAh = sm;
  _Float16* sAl = sm + 5120;
  _Float16* sBh = sm + 10240;
  _Float16* sBl = sm + 10880;
  const int j = blockIdx.x, t = threadIdx.x;
  const int lane = t & 63, wave = t >> 6;
  const int m16 = lane & 15, kg = lane >> 4;
  f4 acc[2];
  acc[0] = (f4)0.f; acc[1] = (f4)0.f;

  for (int kt = 0; kt < 1024; kt += 32) {
#pragma unroll
    for (int it = 0; it < 2; ++it) {
      int idx = t + it * 256;
      int row = idx >> 2, g = idx & 3;
      int lo_ = row * 40 + g * 8;
      size_t ga = (size_t)row * 1024 + kt + g * 8;
      *(h8*)(sAh + lo_) = *(const h8*)(ctxph + ga);
      *(h8*)(sAl + lo_) = *(const h8*)(ctxpl + ga);
    }
    if (t < 64) {
      int row = t >> 2, g = t & 3;
      int lo_ = row * 40 + g * 8;
      size_t gb = (size_t)(j * 16 + row) * 1024 + kt + g * 8;
      *(h8*)(sBh + lo_) = *(const h8*)(WgTh + gb);
      *(h8*)(sBl + lo_) = *(const h8*)(WgTl + gb);
    }
    __syncthreads();
    h8 b_h = *(const h8*)(sBh + m16 * 40 + kg * 8);
    h8 b_l = *(const h8*)(sBl + m16 * 40 + kg * 8);
#pragma unroll
    for (int i = 0; i < 2; ++i) {
      int ro = ((wave * 2 + i) * 16 + m16) * 40 + kg * 8;
      h8 a_h = *(const h8*)(sAh + ro);
      h8 a_l = *(const h8*)(sAl + ro);
      acc[i] = __builtin_amdgcn_mfma_f32_16x16x32_f16(a_h, b_h, acc[i], 0, 0, 0);
      acc[i] = __builtin_amdgcn_mfma_f32_16x16x32_f16(a_h, b_l, acc[i], 0, 0, 0);
      acc[i] = __builtin_amdgcn_mfma_f32_16x16x32_f16(a_l, b_h, acc[i], 0, 0, 0);
    }
    __syncthreads();
  }
  // acc -> gt[row][col]: row = Mtile*16 + kg*4 + reg (b), col = m16 (perm col)
#pragma unroll
  for (int i = 0; i < 2; ++i) {
    int base = (wave * 2 + i) * 16 + kg * 4;
#pragma unroll
    for (int r = 0; r < 4; ++r)
      gt[(base + r) * 17 + m16] = acc[i][r];
  }
  __syncthreads();
  // LSTM pointwise: thread b (<128) handles e = 4j + r, r in 0..4
  if (t < 128) {
    int b = t;
    float dsum = 0.f;
#pragma unroll
    for (int r = 0; r < 4; ++r) {
      int e = j * 4 + r;
      float ig = gt[b * 17 + 0 + r]  + bih[e]        + bhh[e];
      float fg = gt[b * 17 + 4 + r]  + bih[512 + e]  + bhh[512 + e];
      float gg = gt[b * 17 + 8 + r]  + bih[1024 + e] + bhh[1024 + e];
      float og = gt[b * 17 + 12 + r] + bih[1536 + e] + bhh[1536 + e];
      float cprev = cbuf[(size_t)b * 512 + e];
      float c2 = sigm(fg) * cprev + sigm(ig) * tanhf(gg);
      float h2 = sigm(og) * tanhf(c2);
      cbuf[(size_t)b * 512 + e] = c2;
      ctxh[(size_t)b * 1024 + 512 + e] = h2;
      _Float16 hh = (_Float16)h2;
      hph[b * 1024 + 512 + e] = hh;
      hpl[b * 1024 + 512 + e] = (_Float16)(h2 - (float)hh);
      dsum += h2 * done_w[e];
    }
    ddp[b * 128 + j] = dsum;
  }
}

// P2: q-projection + decoder attention fused.  block j: h = j&7, b in
// [(j>>3)*8, +8).  dwq h-slice read from L2.  Writes o[b, h*64..] fp32.
__global__ __launch_bounds__(256) void ph2_k(
    const float* __restrict__ ctxh, const float* __restrict__ dwq,
    const float* __restrict__ dbq,
    const float* __restrict__ Kd, const float* __restrict__ Vd,
    float* __restrict__ obuf)
{
  __shared__ float hbuf[8][512];
  __shared__ float qbuf[8][64];
  __shared__ float sc2[2][320];   // per-half: pv 128 + red 128 (+pad)
  const int j = blockIdx.x, t = threadIdx.x;
  const int h = j & 7, b0 = (j >> 3) * 8;
  // stage h2 for 8 b
  for (int i = t; i < 4096; i += 256) {
    int bi = i >> 9, k = i & 511;
    hbuf[bi][k] = ctxh[(size_t)(b0 + bi) * 1024 + 512 + k];
  }
  __syncthreads();
  // q: 2 batches of 4 b (one per wave), d = lane
  {
    int d = t & 63, bi = t >> 6;
    const float* wcol = dwq + h * 64 + d;
#pragma unroll 1
    for (int batch = 0; batch < 2; ++batch) {
      int bb = batch * 4 + bi;
      float s = 0.f;
      for (int k = 0; k < 512; ++k) s += hbuf[bb][k] * wcol[(size_t)k * 512];
      qbuf[bb][d] = s + dbq[h * 64 + d];
    }
  }
  __syncthreads();
  // attention: 2 half-blocks x 4 rounds (verbatim r4 structure)
  {
    int half = t >> 7, tl = t & 127;
    float* pv = sc2[half];
    float* red = pv + 128;
#pragma unroll 1
    for (int r4 = 0; r4 < 4; ++r4) {
      int item = r4 * 2 + half;
      int b = b0 + item;
      float scv = -3.4e38f;
      if (tl < Nn) {
        const float* kr = Kd + ((size_t)(b * Nn + tl)) * 512 + h * 64;
        float s = 0.f;
#pragma unroll
        for (int d = 0; d < 64; ++d) s += qbuf[item][d] * kr[d];
        scv = s * 0.125f;
      }
      red[tl] = scv; __syncthreads();
      for (int o2 = 64; o2 > 0; o2 >>= 1) { if (tl < o2) red[tl] = fmaxf(red[tl], red[tl + o2]); __syncthreads(); }
      float m = red[0]; __syncthreads();
      float ex = (tl < Nn) ? expf(scv - m) : 0.f;
      red[tl] = ex; __syncthreads();
      for (int o2 = 64; o2 > 0; o2 >>= 1) { if (tl < o2) red[tl] += red[tl + o2]; __syncthreads(); }
      float Z = red[0];
      if (tl < Nn) pv[tl] = ex / Z;
      __syncthreads();
      if (tl < 64) {
        float acc = 0.f;
        const float* vr = Vd + (size_t)(b * Nn) * 512 + h * 64 + tl;
        for (int jj = 0; jj < Nn; ++jj) acc += pv[jj] * vr[(size_t)jj * 512];
        obuf[(size_t)b * 512 + h * 64 + tl] = acc;
      }
      __syncthreads();
    }
  }
}

// P3: per-b: done-sum + complete + wo GEMM + LN + M2 scores + select + ctx.
__global__ __launch_bounds__(256) void ph3_k(
    const float* __restrict__ ddp, const float* __restrict__ done_b,
    const float* __restrict__ obuf, const float* __restrict__ dwo,
    const float* __restrict__ dbo, const float* __restrict__ dlng,
    const float* __restrict__ dlnb,
    const float* __restrict__ M2, const float* __restrict__ sb2,
    const float* __restrict__ ew, const float* __restrict__ sbp,
    const float* __restrict__ rpp,
    const _Float16* __restrict__ embh, const _Float16* __restrict__ embl,
    int* visited, int* ucount, int* complete, int* allvis, int* first, int* prev,
    _Float16* __restrict__ ctxph, _Float16* __restrict__ ctxpl,
    float* __restrict__ out, int step)
{
  __shared__ float ob[512];
  __shared__ float av[512];
  __shared__ float red[256];
  __shared__ int redi[256];
  __shared__ float sc[128];
  __shared__ int cflag;
  const int b = blockIdx.x, t = threadIdx.x;
  // done-sum (deterministic tree over 128 partials)
  red[t] = (t < 128) ? ddp[b * 128 + t] : 0.f;
  __syncthreads();
  for (int o = 128; o > 0; o >>= 1) { if (t < o) red[t] += red[t + o]; __syncthreads(); }
  if (t == 0) {
    float z = red[0] + done_b[0];
    int c = complete[b];
    if (!c && ucount[b] >= Nn && step >= Nn && z > 0.f) { c = 1; complete[b] = 1; }
    cflag = c;
  }
  // stage o[b]
  ob[t] = obuf[(size_t)b * 512 + t];
  ob[t + 256] = obuf[(size_t)b * 512 + t + 256];
  __syncthreads();
  // wo GEMM: 2 cols per thread
  float v[2];
#pragma unroll
  for (int r = 0; r < 2; ++r) {
    int col = t + r * 256;
    float s = dbo[col];
    const float* wcol = dwo + col;
    for (int k = 0; k < 512; ++k) s += ob[k] * wcol[(size_t)k * 512];
    v[r] = s;
  }
  __syncthreads();
  // LN
  red[t] = v[0] + v[1]; __syncthreads();
  for (int o = 128; o > 0; o >>= 1) { if (t < o) red[t] += red[t + o]; __syncthreads(); }
  float mu = red[0] * (1.f / 512.f);
  __syncthreads();
  float d0 = v[0] - mu, d1 = v[1] - mu;
  red[t] = d0 * d0 + d1 * d1; __syncthreads();
  for (int o = 128; o > 0; o >>= 1) { if (t < o) red[t] += red[t + o]; __syncthreads(); }
  float inv = 1.f / sqrtf(red[0] * (1.f / 512.f) + 1e-5f);
  av[t] = d0 * inv * dlng[t] + dlnb[t];
  av[t + 256] = d1 * inv * dlng[t + 256] + dlnb[t + 256];
  __syncthreads();
  // scores via M2
  if (t < Nn) {
    const float* m2r = M2 + ((size_t)(b * Nn + t)) * 512;
    float s = sb2[b * Nn + t];
    for (int jj = 0; jj < 512; ++jj) s += av[jj] * m2r[jj];
    int avz = allvis[b];
    if (!avz && visited[b * Nn + t]) s = rpp[0];
    if (avz) {
      int pvn = prev[b];
      float direct = ew[(size_t)b * 10000 + (size_t)pvn * 100];
      float via = ew[(size_t)b * 10000 + (size_t)pvn * 100 + t]
                + ew[(size_t)b * 10000 + (size_t)t * 100];
      if (via < direct) s += sbp[0] * (direct - via) / direct;
    }
    if (cflag) s = (t == first[b]) ? 100.f : -1e9f;
    sc[t] = s;
  }
  __syncthreads();
  // argmax + softmax + select (verbatim proven)
  float vv = (t < Nn) ? sc[t] : -3.4e38f;
  int ii = (t < Nn) ? t : 0x7fffffff;
  red[t] = vv; redi[t] = ii;
  __syncthreads();
  for (int o = 128; o > 0; o >>= 1) {
    if (t < o) {
      float v2 = red[t + o]; int i2 = redi[t + o];
      if (v2 > red[t] || (v2 == red[t] && i2 < redi[t])) { red[t] = v2; redi[t] = i2; }
    }
    __syncthreads();
  }
  float m = red[0];
  int curr = redi[0];
  __syncthreads();
  float ex = (t < Nn) ? expf(sc[t] - m) : 0.f;
  red[t] = ex; __syncthreads();
  for (int o = 128; o > 0; o >>= 1) { if (t < o) red[t] += red[t + o]; __syncthreads(); }
  float Z = red[0];
  if (t == 0) {
    float pcur = expf(sc[curr] - m) / Z;
    out[step * Bb + b] = logf(pcur + 1e-10f);
    out[(151 + step) * Bb + b] = (float)curr;
    if (!cflag) {
      if (!visited[b * Nn + curr]) ucount[b] = ucount[b] + 1;
      visited[b * Nn + curr] = 1;
    }
    if (ucount[b] >= Nn) allvis[b] = 1;
    if (step == 0) first[b] = curr;
    prev[b] = curr;
  }
  size_t src = ((size_t)(b * Nn) + (size_t)curr) * 512;
  ctxph[b * 1024 + t]       = embh[src + t];
  ctxph[b * 1024 + t + 256] = embh[src + t + 256];
  ctxpl[b * 1024 + t]       = embl[src + t];
  ctxpl[b * 1024 + t + 256] = embl[src + t + 256];
}

__global__ void final_k(const int* complete, const int* first, float* out)
{
  int b = threadIdx.x;
  out[(151 + 150) * Bb + b] = complete[b] ? 0.f : (float)first[b];
}

// ---------------------------------------------------------------------------
extern "C" void kernel_launch(void* const* d_in, const int* in_sizes, int n_in,
                              void* d_out, int out_size, void* d_ws, size_t ws_size,
                              hipStream_t stream)
{
  const float* nf      = (const float*)d_in[0];
  const float* ew      = (const float*)d_in[1];
  const float* pe      = (const float*)d_in[2];
  const float* in_w    = (const float*)d_in[3];
  const float* in_b    = (const float*)d_in[4];
  const float* enc_wq  = (const float*)d_in[5];
  const float* enc_wk  = (const float*)d_in[6];
  const float* enc_wv  = (const float*)d_in[7];
  const float* enc_wo  = (const float*)d_in[8];
  const float* enc_bq  = (const float*)d_in[9];
  const float* enc_bk  = (const float*)d_in[10];
  const float* enc_bv  = (const float*)d_in[11];
  const float* enc_bo  = (const float*)d_in[12];
  const float* enc_w1  = (const float*)d_in[13];
  const float* enc_b1  = (const float*)d_in[14];
  const float* enc_w2  = (const float*)d_in[15];
  const float* enc_b2  = (const float*)d_in[16];
  const float* ln1g    = (const float*)d_in[17];
  const float* ln1b    = (const float*)d_in[18];
  const float* ln2g    = (const float*)d_in[19];
  const float* ln2b    = (const float*)d_in[20];
  const float* wih     = (const float*)d_in[21];
  const float* whh     = (const float*)d_in[22];
  const float* bih     = (const float*)d_in[23];
  const float* bhh     = (const float*)d_in[24];
  const float* dwq     = (const float*)d_in[25];
  const float* dwk     = (const float*)d_in[26];
  const float* dwv     = (const float*)d_in[27];
  const float* dwo     = (const float*)d_in[28];
  const float* dpw     = (const float*)d_in[29];
  const float* dbq     = (const float*)d_in[30];
  const float* dbk     = (const float*)d_in[31];
  const float* dbv     = (const float*)d_in[32];
  const float* dbo     = (const float*)d_in[33];
  const float* dpb     = (const float*)d_in[34];
  const float* dlng    = (const float*)d_in[35];
  const float* dlnb    = (const float*)d_in[36];
  const float* sbp     = (const float*)d_in[37];
  const float* rpp     = (const float*)d_in[38];
  const float* done_w  = (const float*)d_in[39];
  const float* done_b  = (const float*)d_in[40];
  float* out = (float*)d_out;

  // ---- workspace carve ----
  const size_t SZ = 12800ull * 512;
  float* ws = (float*)d_ws;
  float* x   = ws;
  float* xq  = x + SZ;                          // enc scratch -> M2
  float* xk  = xq + SZ;                         // enc k -> dec K
  float* xv  = xk + SZ;                         // enc v / ff2 partials -> dec V
  _Float16* xh = (_Float16*)(xv + SZ);          // node_emb planes
  _Float16* xl = xh + SZ;
  _Float16* oh = xl + SZ;                       // enc scratch planes
  _Float16* ol = oh + SZ;
  _Float16* wb = ol + SZ;                       // weight-plane region (12.6 MB)
  _Float16* wqh = wb;               _Float16* wql = wqh + 262144;
  _Float16* wkh = wql + 262144;     _Float16* wkl = wkh + 262144;
  _Float16* wvh = wkl + 262144;     _Float16* wvl = wvh + 262144;
  _Float16* woh_ = wvl + 262144;    _Float16* wol_ = woh_ + 262144;
  _Float16* w1h = wol_ + 262144;    _Float16* w1l = w1h + 1048576;
  _Float16* w2h = w1l + 1048576;    _Float16* w2l = w2h + 1048576;
  // decode region (small, after wb)
  float* tail   = (float*)(w2l + 1048576);
  float* sb2    = tail;                         // 12800
  float* ddp    = sb2 + 12800;                  // 128*128
  float* obuf   = ddp + 16384;                  // 128*512
  float* ctxh   = obuf + 65536;                 // 128*1024 (h half used fp32)
  float* cbuf   = ctxh + 131072;                // 128*512
  _Float16* ctxph = (_Float16*)(cbuf + 65536);  // 128*1024 planes
  _Float16* ctxpl = ctxph + 131072;
  int* ivis     = (int*)(ctxpl + 131072);       // 128*100
  int* ucount   = ivis + 12800;
  int* complete = ucount + 128;
  int* allvis   = complete + 128;
  int* first    = allvis + 128;
  int* prev     = first + 128;
  float* M2 = xq;

  // ---- encoder (proven, unchanged) ----
  input_proj_k<<<25600, 256, 0, stream>>>(nf, in_w, in_b, pe, x, xh, xl);

  for (int l = 0; l < Ll; ++l) {
    const float* wq = enc_wq + (size_t)l * 262144;
    const float* wk = enc_wk + (size_t)l * 262144;
    const float* wv = enc_wv + (size_t)l * 262144;
    const float* wo = enc_wo + (size_t)l * 262144;
    const float* bq = enc_bq + (size_t)l * 512;
    const float* bk = enc_bk + (size_t)l * 512;
    const float* bv = enc_bv + (size_t)l * 512;
    const float* bo = enc_bo + (size_t)l * 512;
    const float* w1 = enc_w1 + (size_t)l * 1048576;
    const float* b1 = enc_b1 + (size_t)l * 2048;
    const float* w2 = enc_w2 + (size_t)l * 1048576;
    const float* b2 = enc_b2 + (size_t)l * 512;

    wconv_k<<<dim3(16, 16), 256, 0, stream>>>(wq, 512, 512, wqh, wql);
    wconv_k<<<dim3(16, 16), 256, 0, stream>>>(wk, 512, 512, wkh, wkl);
    wconv_k<<<dim3(16, 16), 256, 0, stream>>>(wv, 512, 512, wvh, wvl);
    wconv_k<<<dim3(16, 16), 256, 0, stream>>>(wo, 512, 512, woh_, wol_);
    wconv_k<<<dim3(64, 16), 256, 0, stream>>>(w1, 512, 2048, w1h, w1l);
    wconv_k<<<dim3(16, 64), 256, 0, stream>>>(w2, 2048, 512, w2h, w2l);

    mgemm_k<false, true, true, false><<<dim3(4, 100), 256, 0, stream>>>(
        xh, xl, 512, wqh, wql, 512, xq, nullptr, nullptr, 512, bq, 512, 0, 0);
    mgemm_k<false, true, true, false><<<dim3(4, 100), 256, 0, stream>>>(
        xh, xl, 512, wkh, wkl, 512, xk, nullptr, nullptr, 512, bk, 512, 0, 0);
    mgemm_k<false, true, true, false><<<dim3(4, 100), 256, 0, stream>>>(
        xh, xl, 512, wvh, wvl, 512, xv, nullptr, nullptr, 512, bv, 512, 0, 0);
    enc_attn_k<<<1024, 256, 0, stream>>>(xq, xk, xv, oh, ol);
    mgemm_k<false, true, true, false><<<dim3(4, 100), 256, 0, stream>>>(
        oh, ol, 512, woh_, wol_, 512, xq, nullptr, nullptr, 512, bo, 512, 0, 0);
    ln_k<<<12800, 256, 0, stream>>>(x, xq, ln1g + l * 512, ln1b + l * 512, x, xh, xl);
    for (int c = 0; c < 4; ++c) {
      mgemm_k<true, true, false, false><<<dim3(16, 25), 256, 0, stream>>>(
          xh + (size_t)c * 3200 * 512, xl + (size_t)c * 3200 * 512, 512,
          w1h, w1l, 512, nullptr, oh, ol, 2048, b1, 512, 0, 0);
      mgemm_k<false, false, true, true><<<dim3(4, 25, 4), 256, 0, stream>>>(
          oh, ol, 2048, w2h, w2l, 2048, xv, nullptr, nullptr, 512,
          nullptr, 2048, 512, 3200);
      reduce4_k<<<6400, 256, 0, stream>>>(xv, b2, xq + (size_t)c * 3200 * 512);
    }
    ln_k<<<12800, 256, 0, stream>>>(x, xq, ln2g + l * 512, ln2b + l * 512, x, xh, xl);
  }

  // ---- decode prep ----
  wconv_k<<<dim3(16, 16), 256, 0, stream>>>(dwk, 512, 512, wqh, wql);
  wconv_k<<<dim3(16, 16), 256, 0, stream>>>(dwv, 512, 512, wkh, wkl);
  mgemm_k<false, true, true, false><<<dim3(4, 100), 256, 0, stream>>>(
      xh, xl, 512, wqh, wql, 512, xk, nullptr, nullptr, 512, dbk, 512, 0, 0);
  mgemm_k<false, true, true, false><<<dim3(4, 100), 256, 0, stream>>>(
      xh, xl, 512, wkh, wkl, 512, xv, nullptr, nullptr, 512, dbv, 512, 0, 0);
  // WgTperm planes + dpw planes live in wb region (free after encoder)
  _Float16* WgTh = wb;                          // 2048*1024
  _Float16* WgTl = WgTh + 2097152;
  _Float16* dpwNh = WgTl + 2097152;             // 512*512
  _Float16* dpwNl = dpwNh + 262144;
  wconvg_k<<<2048, 256, 0, stream>>>(wih, whh, WgTh, WgTl);
  wsplit_k<<<1024, 256, 0, stream>>>(dpw, dpwNh, dpwNl, 262144);
  mgemm_k<false, false, true, false><<<dim3(4, 100), 256, 0, stream>>>(
      xh, xl, 512, dpwNh, dpwNl, 512, M2, nullptr, nullptr, 512, nullptr, 512, 0, 0);
  sb2_k<<<3200, 256, 0, stream>>>(x, dpb, sb2);
  init2_k<<<128, 256, 0, stream>>>(x, ctxph, ctxpl, ctxh, cbuf, ivis, ucount,
                                   complete, allvis, first, prev, out);

  // ---- decode loop: 3 launches/step ----
  for (int step = 0; step < STEPS; ++step) {
    ph1_k<<<128, 256, 0, stream>>>(ctxph, ctxpl, WgTh, WgTl, bih, bhh,
                                   cbuf, ctxh, ctxph, ctxpl, done_w, ddp);
    ph2_k<<<128, 256, 0, stream>>>(ctxh, dwq, dbq, xk, xv, obuf);
    ph3_k<<<128, 256, 0, stream>>>(ddp, done_b, obuf, dwo, dbo, dlng, dlnb,
                                   M2, sb2, ew, sbp, rpp, xh, xl,
                                   ivis, ucount, complete, allvis, first, prev,
                                   ctxph, ctxpl, out, step);
  }
  final_k<<<1, 128, 0, stream>>>(complete, first, out);
}